// Round 12
// baseline (111.541 us; speedup 1.0000x reference)
//
#include <hip/hip_runtime.h>
#include <stdint.h>

#define ND   4096               // row stride (floats) for x / upfold / out
#define NST  8                  // super-tiles of 128 o-rows
#define BUFB 35840              // per-buffer bytes: Ub 18432 + Ut2 17408

typedef float    floatx16 __attribute__((ext_vector_type(16)));
typedef _Float16 half8    __attribute__((ext_vector_type(8)));
typedef _Float16 h2       __attribute__((ext_vector_type(2)));
typedef __fp16   fp16x2   __attribute__((ext_vector_type(2)));

__device__ __forceinline__ uint32_t pkh2(float a, float b) {
    fp16x2 p = __builtin_amdgcn_cvt_pkrtz(a, b);   // v_cvt_pkrtz_f16_f32
    return __builtin_bit_cast(uint32_t, p);
}

__device__ __forceinline__ half8 mk_frag(uint32_t a, uint32_t b, uint32_t c, uint32_t d) {
    union { uint32_t u[4]; half8 v; } U;
    U.u[0] = a; U.u[1] = b; U.u[2] = c; U.u[3] = d;
    return U.v;
}

// sigmoid(s/8) - 0.5 = 0.5*tanh(s/16), odd poly in v=(s/16)^2, packed fp16.
__device__ __forceinline__ uint32_t psig(float s0, float s1) {
    const h2 HI = {(_Float16)41.6f,        (_Float16)41.6f};
    const h2 LO = {(_Float16)-41.6f,       (_Float16)-41.6f};
    const h2 SC = {(_Float16)0.0625f,      (_Float16)0.0625f};
    const h2 C0 = {(_Float16)0.03099238f,  (_Float16)0.03099238f};
    const h2 C1 = {(_Float16)-0.00842090f, (_Float16)-0.00842090f};
    const h2 C2 = {(_Float16)0.00151845f,  (_Float16)0.00151845f};
    const h2 C3 = {(_Float16)-1.02197e-4f, (_Float16)-1.02197e-4f};
    h2 s = __builtin_bit_cast(h2, pkh2(s0, s1));
    s = __builtin_elementwise_min(s, HI);
    s = __builtin_elementwise_max(s, LO);
    h2 ha = s * SC;
    h2 v  = ha * ha;
    h2 w  = C2 + v * C3;
    w     = C1 + v * w;
    w     = C0 + v * w;
    h2 f  = s * w;
    return __builtin_bit_cast(uint32_t, f);
}

__global__ void __launch_bounds__(256, 1)
corr_kernel(const float* __restrict__ x, const float* __restrict__ up,
            float* __restrict__ out)
{
    __shared__ __align__(16) uint8_t smem[2 * BUFB];   // dbuf; Xs overlay in init

    const int tid  = threadIdx.x;
    const int lane = tid & 63;
    const int wid  = tid >> 6;
    const int l31  = lane & 31;
    const int h    = lane >> 5;          // wave half
    const int r8   = tid >> 4;           // staging row-group (0..15)
    const int c    = tid & 15;           // staging col quad: d = 4c..4c+3
    const int n    = blockIdx.x;         // XCD swizzle: same n -> same XCD
    const int lb   = blockIdx.y;

    const float* ubase = up + (size_t)n * 64;

    // coalesced 128-o super-tile load: rows 2r8+32j (va) / +1 (vb), cols 4c..4c+3
    float4 va[4], vb[4];
    auto load_super = [&](int st) {
        const float* pr = ubase + (size_t)(st * 128 + 2 * r8) * ND + 4 * c;
        #pragma unroll
        for (int j = 0; j < 4; ++j) {
            va[j] = *(const float4*)(pr + (size_t)(32 * j) * ND);
            vb[j] = *(const float4*)(pr + (size_t)(32 * j) * ND + ND);
        }
    };
    auto stage_super = [&](int b) {
        uint16_t (*Ub)[72]  = (uint16_t (*)[72])(smem + b * BUFB);
        uint32_t (*Ut2)[68] = (uint32_t (*)[68])(smem + b * BUFB + 18432);
        #pragma unroll
        for (int j = 0; j < 4; ++j) {
            *(uint2*)&Ub[2*r8 + 32*j][4*c] =
                make_uint2(pkh2(va[j].x, va[j].y), pkh2(va[j].z, va[j].w));
            *(uint2*)&Ub[2*r8 + 32*j + 1][4*c] =
                make_uint2(pkh2(vb[j].x, vb[j].y), pkh2(vb[j].z, vb[j].w));
            *(uint4*)&Ut2[r8 + 16*j][4*c] =
                make_uint4(pkh2(va[j].x, vb[j].x), pkh2(va[j].y, vb[j].y),
                           pkh2(va[j].z, vb[j].z), pkh2(va[j].w, vb[j].w));
        }
    };

    load_super(0);   // longest-latency path first

    // ---- phase 0: X tile (256 rows) -> LDS fp32 (overlay), build 2 Xf sets ----
    half8 Xf[2][4];
    {
        float (*Xs)[68] = (float (*)[68])smem;     // 256 x 68 f32 = 69632 B overlay
        const int m  = tid & 15;                   // float4 column
        const int r0 = tid >> 4;                   // row base
        const float* xbase = x + (size_t)(lb * 256 + r0) * ND + n * 64 + 4 * m;
        #pragma unroll
        for (int k = 0; k < 16; ++k)
            *(float4*)&Xs[r0 + 16*k][4*m] = *(const float4*)(xbase + (size_t)(16*k) * ND);
        __syncthreads();
        #pragma unroll
        for (int lg = 0; lg < 2; ++lg) {
            const int rl = wid * 64 + lg * 32 + l31;
            #pragma unroll
            for (int kk = 0; kk < 4; ++kk) {
                float4 f1 = *(const float4*)&Xs[rl][16 * kk + 8 * h];
                float4 f2 = *(const float4*)&Xs[rl][16 * kk + 8 * h + 4];
                Xf[lg][kk] = mk_frag(pkh2(f1.x, f1.y), pkh2(f1.z, f1.w),
                                     pkh2(f2.x, f2.y), pkh2(f2.z, f2.w));
            }
        }
        __syncthreads();   // all Xs reads done before buf0 staging overwrites
    }

    stage_super(0);
    load_super(1);
    __syncthreads();

    floatx16 F[2][2];   // [l-group][d-half] accumulators
    #pragma unroll
    for (int lg = 0; lg < 2; ++lg)
        #pragma unroll
        for (int i = 0; i < 16; ++i) { F[lg][0][i] = 0.0f; F[lg][1][i] = 0.0f; }

    for (int st = 0; st < NST; ++st) {
        const int b = st & 1;
        uint16_t (*Ub)[72] = (uint16_t (*)[72])(smem + b * BUFB);
        const uint32_t* utp = (const uint32_t*)(smem + b * BUFB + 18432);

        #pragma unroll
        for (int sub = 0; sub < 2; ++sub) {
            const int ob = 64 * sub;
            // GEMM1 A-frags (U rows) — reused across both l-groups
            half8 A0k[4], A1k[4];
            #pragma unroll
            for (int kk = 0; kk < 4; ++kk) {
                A0k[kk] = *(const half8*)&Ub[ob + l31][16 * kk + 8 * h];
                A1k[kk] = *(const half8*)&Ub[ob + 32 + l31][16 * kk + 8 * h];
            }
            // GEMM2 A-frags (U^T gather) — reused across both l-groups
            uint32_t ga[4][4], gb[4][4];
            const int opb0 = 32 * sub + 4 * h;
            #pragma unroll
            for (int c2 = 0; c2 < 4; ++c2)
                #pragma unroll
                for (int k = 0; k < 4; ++k) {          // 2 lanes/bank = free
                    ga[c2][k] = utp[(opb0 + 8*c2 + k) * 68 + l31];
                    gb[c2][k] = utp[(opb0 + 8*c2 + k) * 68 + 32 + l31];
                }
            if (sub == 0) {   // overlap staging + prefetch with the long compute
                if (st + 1 < NST) stage_super(b ^ 1);
                if (st + 2 < NST) load_super(st + 2);
            }
            #pragma unroll
            for (int lg = 0; lg < 2; ++lg) {
                // GEMM1: S^T = U * X^T
                floatx16 S0, S1;
                #pragma unroll
                for (int i = 0; i < 16; ++i) { S0[i] = 0.0f; S1[i] = 0.0f; }
                #pragma unroll
                for (int kk = 0; kk < 4; ++kk) {
                    S0 = __builtin_amdgcn_mfma_f32_32x32x16_f16(A0k[kk], Xf[lg][kk], S0, 0, 0, 0);
                    S1 = __builtin_amdgcn_mfma_f32_32x32x16_f16(A1k[kk], Xf[lg][kk], S1, 0, 0, 0);
                }
                // sigmoid weights
                uint32_t P[16];
                #pragma unroll
                for (int m = 0; m < 8; ++m) P[m]     = psig(S0[2*m], S0[2*m+1]);
                #pragma unroll
                for (int m = 0; m < 8; ++m) P[8 + m] = psig(S1[2*m], S1[2*m+1]);
                // GEMM2: F^T += U^T * W
                uint32_t R[8];
                #pragma unroll
                for (int c2 = 0; c2 < 4; ++c2) {
                    const uint32_t* Q = P + (c2 >> 1) * 8;
                    const int t4 = (c2 & 1) * 4;
                    R[2*c2]   = __shfl_xor(h ? Q[t4]     : Q[t4 + 2], 32);
                    R[2*c2+1] = __shfl_xor(h ? Q[t4 + 1] : Q[t4 + 3], 32);
                }
                #pragma unroll
                for (int c2 = 0; c2 < 4; ++c2) {
                    const uint32_t* Q = P + (c2 >> 1) * 8;
                    const int t4 = (c2 & 1) * 4;
                    half8 B = h ? mk_frag(R[2*c2], R[2*c2+1], Q[t4 + 2], Q[t4 + 3])
                                : mk_frag(Q[t4], Q[t4 + 1], R[2*c2], R[2*c2+1]);
                    half8 A0 = mk_frag(ga[c2][0], ga[c2][1], ga[c2][2], ga[c2][3]);
                    half8 A1 = mk_frag(gb[c2][0], gb[c2][1], gb[c2][2], gb[c2][3]);
                    F[lg][0] = __builtin_amdgcn_mfma_f32_32x32x16_f16(A0, B, F[lg][0], 0, 0, 0);
                    F[lg][1] = __builtin_amdgcn_mfma_f32_32x32x16_f16(A1, B, F[lg][1], 0, 0, 0);
                }
            }
        }
        __syncthreads();   // one barrier per 128-o super-tile
    }

    // ---- epilogue: direct store, two l-groups ----
    #pragma unroll
    for (int lg = 0; lg < 2; ++lg) {
        float* op = out + (size_t)(lb * 256 + wid * 64 + lg * 32 + l31) * ND + n * 64;
        #pragma unroll
        for (int q = 0; q < 4; ++q) {
            float4 a; a.x = F[lg][0][4*q]; a.y = F[lg][0][4*q+1];
                      a.z = F[lg][0][4*q+2]; a.w = F[lg][0][4*q+3];
            *(float4*)(op + 8*q + 4*h) = a;               // d 0..31
            float4 bq; bq.x = F[lg][1][4*q]; bq.y = F[lg][1][4*q+1];
                       bq.z = F[lg][1][4*q+2]; bq.w = F[lg][1][4*q+3];
            *(float4*)(op + 32 + 8*q + 4*h) = bq;         // d 32..63
        }
    }
}

extern "C" void kernel_launch(void* const* d_in, const int* in_sizes, int n_in,
                              void* d_out, int out_size, void* d_ws, size_t ws_size,
                              hipStream_t stream)
{
    const float* x  = (const float*)d_in[0];
    const float* up = (const float*)d_in[1];
    float* out      = (float*)d_out;
    corr_kernel<<<dim3(64, 4), dim3(256), 0, stream>>>(x, up, out);
}